// Round 1
// baseline (1305.314 us; speedup 1.0000x reference)
//
#include <hip/hip_runtime.h>
#include <hip/hip_bf16.h>

#define FDIM 128

__device__ __forceinline__ float sp(float x) {
    // softplus = log(1+exp(x)), numerically stable (== jnp.logaddexp(x,0))
    return fmaxf(x, 0.0f) + log1pf(expf(-fabsf(x)));
}

// Y[r][:] = POST( PRE(X[r][:]) @ W + bias ) (+ residual)
// PRE : 0 = identity, 1 = softplus
// POST: 0 = none, 1 = softplus, 2 = softplus(softplus(.))
// RES : 0 = none, 1 = + resid[r][c], 2 = + gate[c]*resid[r][c]
template<int PRE, int POST, int RES>
__global__ __launch_bounds__(256) void gemm_f32(
    const float* __restrict__ X, const float* __restrict__ W,
    const float* __restrict__ bias, const float* __restrict__ resid,
    const float* __restrict__ gate, float* __restrict__ Y, int nrows)
{
    __shared__ float Ws[64 * FDIM];  // 32 KB: K-half of W, [64][128]
    __shared__ float Xs[64 * 64];    // 16 KB: 64 rows x 64 k, PRE applied

    const int t     = threadIdx.x;
    const int cg    = t & 31;   // column group: cols 4cg..4cg+3
    const int rbase = t >> 5;   // 0..7
    const int row0  = blockIdx.x * 64;

    float4 acc[8];
#pragma unroll
    for (int i = 0; i < 8; ++i) acc[i] = make_float4(0.f, 0.f, 0.f, 0.f);

    for (int kh = 0; kh < 2; ++kh) {
        __syncthreads();  // protect previous half's reads before overwrite
        // stage W[kh*64 .. kh*64+63][0..127]
        {
            const float4* Wg4 = (const float4*)(W + (size_t)kh * 64 * FDIM);
            float4* Ws4 = (float4*)Ws;
#pragma unroll
            for (int i = 0; i < 8; ++i) Ws4[t + 256 * i] = Wg4[t + 256 * i];
        }
        // stage X[row0..row0+63][kh*64 .. kh*64+63], applying PRE
        {
#pragma unroll
            for (int i = 0; i < 4; ++i) {
                int idx = t + 256 * i;       // 0..1023 float4 slots
                int r   = idx >> 4;          // 16 float4 per row
                int c4  = (idx & 15) * 4;
                int gr  = row0 + r;
                float4 v = make_float4(0.f, 0.f, 0.f, 0.f);
                if (gr < nrows)
                    v = *(const float4*)(X + (size_t)gr * FDIM + kh * 64 + c4);
                if (PRE == 1) { v.x = sp(v.x); v.y = sp(v.y); v.z = sp(v.z); v.w = sp(v.w); }
                *(float4*)(Xs + r * 64 + c4) = v;
            }
        }
        __syncthreads();

        const float4* Ws4 = (const float4*)Ws;
#pragma unroll 4
        for (int k = 0; k < 64; ++k) {
            float4 w = Ws4[k * 32 + cg];
#pragma unroll
            for (int pass = 0; pass < 8; ++pass) {
                float xv = Xs[(pass * 8 + rbase) * 64 + k];
                acc[pass].x += xv * w.x;
                acc[pass].y += xv * w.y;
                acc[pass].z += xv * w.z;
                acc[pass].w += xv * w.w;
            }
        }
    }

    // epilogue
    float4 b4 = *(const float4*)(bias + cg * 4);
#pragma unroll
    for (int pass = 0; pass < 8; ++pass) {
        int gr = row0 + pass * 8 + rbase;
        if (gr >= nrows) continue;
        float4 o = acc[pass];
        o.x += b4.x; o.y += b4.y; o.z += b4.z; o.w += b4.w;
        if (POST >= 1) { o.x = sp(o.x); o.y = sp(o.y); o.z = sp(o.z); o.w = sp(o.w); }
        if (POST == 2) { o.x = sp(o.x); o.y = sp(o.y); o.z = sp(o.z); o.w = sp(o.w); }
        if (RES == 1) {
            float4 rv = *(const float4*)(resid + (size_t)gr * FDIM + cg * 4);
            o.x += rv.x; o.y += rv.y; o.z += rv.z; o.w += rv.w;
        }
        if (RES == 2) {
            float4 rv = *(const float4*)(resid + (size_t)gr * FDIM + cg * 4);
            float4 g4 = *(const float4*)(gate + cg * 4);
            o.x += g4.x * rv.x; o.y += g4.y * rv.y; o.z += g4.z * rv.z; o.w += g4.w * rv.w;
        }
        *(float4*)(Y + (size_t)gr * FDIM + cg * 4) = o;
    }
}

// For each pair p: g = f_ij[p] @ Wg (recomputed in-register), then
// xi[idx_i[p]] += g * xj[idx_j[p]]   (hardware f32 atomics)
__global__ __launch_bounds__(256) void pair_scatter(
    const float* __restrict__ f_ij, const int* __restrict__ idx_i,
    const int* __restrict__ idx_j, const float* __restrict__ Wg,
    const float* __restrict__ xj, float* __restrict__ xi, int npairs)
{
    __shared__ float Wgs[16 * FDIM];  // 8 KB
    {
        const float4* g4 = (const float4*)Wg;
        float4* s4 = (float4*)Wgs;
        s4[threadIdx.x] = g4[threadIdx.x];
        s4[threadIdx.x + 256] = g4[threadIdx.x + 256];
    }
    __syncthreads();

    const int lane = threadIdx.x & 63;
    const int p = blockIdx.x * 4 + (threadIdx.x >> 6);
    if (p >= npairs) return;

    const int ai = idx_i[p];
    const int aj = idx_j[p];

    float fr[16];
#pragma unroll
    for (int i = 0; i < 4; ++i) {
        float4 v = *(const float4*)(f_ij + (size_t)p * 16 + i * 4);
        fr[4 * i + 0] = v.x; fr[4 * i + 1] = v.y; fr[4 * i + 2] = v.z; fr[4 * i + 3] = v.w;
    }

    float g0 = 0.f, g1 = 0.f;
#pragma unroll
    for (int r = 0; r < 16; ++r) {
        float2 w = *(const float2*)(Wgs + r * FDIM + lane * 2);
        g0 += fr[r] * w.x;
        g1 += fr[r] * w.y;
    }

    float2 xv = *(const float2*)(xj + (size_t)aj * FDIM + lane * 2);
    float* dst = xi + (size_t)ai * FDIM + lane * 2;
    unsafeAtomicAdd(dst + 0, g0 * xv.x);
    unsafeAtomicAdd(dst + 1, g1 * xv.y);
}

// prediction[r][0..1] = y[r][:] @ Wout + bout ; one wave per row
__global__ __launch_bounds__(256) void out_proj(
    const float* __restrict__ y, const float* __restrict__ Wout,
    const float* __restrict__ bout, float* __restrict__ pred, int nrows)
{
    const int lane = threadIdx.x & 63;
    const int r = blockIdx.x * 4 + (threadIdx.x >> 6);
    if (r >= nrows) return;

    float v0 = y[(size_t)r * FDIM + lane];
    float v1 = y[(size_t)r * FDIM + 64 + lane];
    float2 w0 = ((const float2*)Wout)[lane];
    float2 w1 = ((const float2*)Wout)[lane + 64];
    float a = v0 * w0.x + v1 * w1.x;
    float b = v0 * w0.y + v1 * w1.y;
#pragma unroll
    for (int o = 32; o > 0; o >>= 1) {
        a += __shfl_down(a, o, 64);
        b += __shfl_down(b, o, 64);
    }
    if (lane == 0) {
        pred[(size_t)r * 2 + 0] = a + bout[0];
        pred[(size_t)r * 2 + 1] = b + bout[1];
    }
}

extern "C" void kernel_launch(void* const* d_in, const int* in_sizes, int n_in,
                              void* d_out, int out_size, void* d_ws, size_t ws_size,
                              hipStream_t stream)
{
    const float* emb     = (const float*)d_in[0];
    const float* f_ij    = (const float*)d_in[1];
    const int*   idx_i   = (const int*)d_in[2];
    const int*   idx_j   = (const int*)d_in[3];
    const float* Wi      = (const float*)d_in[4];
    const float* bi      = (const float*)d_in[5];
    const float* Wj      = (const float*)d_in[6];
    const float* bj      = (const float*)d_in[7];
    const float* Wg      = (const float*)d_in[8];
    const float* Wv      = (const float*)d_in[9];
    const float* bv      = (const float*)d_in[10];
    const float* gate    = (const float*)d_in[11];
    const float* res_w1  = (const float*)d_in[12];
    const float* res_b1  = (const float*)d_in[13];
    const float* res_w2  = (const float*)d_in[14];
    const float* res_b2  = (const float*)d_in[15];
    const float* ores_w1 = (const float*)d_in[16];
    const float* ores_b1 = (const float*)d_in[17];
    const float* ores_w2 = (const float*)d_in[18];
    const float* ores_b2 = (const float*)d_in[19];
    const float* Wout    = (const float*)d_in[20];
    const float* bout    = (const float*)d_in[21];

    const int N = in_sizes[0] / FDIM;   // 50000
    const int P = in_sizes[2];          // 800000

    float* xi   = (float*)d_ws;                         // [N,128]
    float* buf  = xi + (size_t)N * FDIM;                // [N,128] shared: xj -> h -> y
    float* xj   = buf;
    float* h    = buf;   // alive only after xj dead (post pair_scatter)
    float* y    = buf;   // X==Y aliasing safe: blocks touch disjoint row ranges
    float* pred    = (float*)d_out;                     // [N,2]
    float* updated = (float*)d_out + (size_t)N * 2;     // [N,128]

    const dim3 blk(256);
    const int ggrid = (N + 63) / 64;

    // xi = act(act(emb @ Wi + bi)); xj = act(act(emb @ Wj + bj))
    gemm_f32<0, 2, 0><<<ggrid, blk, 0, stream>>>(emb, Wi, bi, nullptr, nullptr, xi, N);
    gemm_f32<0, 2, 0><<<ggrid, blk, 0, stream>>>(emb, Wj, bj, nullptr, nullptr, xj, N);

    // xi[idx_i] += (f_ij @ Wg) * xj[idx_j]
    pair_scatter<<<(P + 3) / 4, blk, 0, stream>>>(f_ij, idx_i, idx_j, Wg, xj, xi, P);

    // 3 residual blocks: xi = xi + act(act(xi)@w1+b1)@w2 + b2
    for (int k = 0; k < 3; ++k) {
        gemm_f32<1, 1, 0><<<ggrid, blk, 0, stream>>>(
            xi, res_w1 + (size_t)k * FDIM * FDIM, res_b1 + (size_t)k * FDIM,
            nullptr, nullptr, h, N);
        gemm_f32<0, 0, 1><<<ggrid, blk, 0, stream>>>(
            h, res_w2 + (size_t)k * FDIM * FDIM, res_b2 + (size_t)k * FDIM,
            xi, nullptr, xi, N);
    }

    // updated = gate*emb + act(xi)@Wv + bv   (written straight to d_out)
    gemm_f32<1, 0, 2><<<ggrid, blk, 0, stream>>>(xi, Wv, bv, emb, gate, updated, N);

    // output residual block on updated -> y
    gemm_f32<1, 1, 0><<<ggrid, blk, 0, stream>>>(updated, ores_w1, ores_b1,
                                                 nullptr, nullptr, h, N);
    gemm_f32<0, 0, 1><<<ggrid, blk, 0, stream>>>(h, ores_w2, ores_b2,
                                                 updated, nullptr, y, N);

    // prediction = y @ Wout + bout
    out_proj<<<(N + 3) / 4, blk, 0, stream>>>(y, Wout, bout, pred, N);
}